// Round 1
// baseline (333.177 us; speedup 1.0000x reference)
//
#include <hip/hip_runtime.h>

// Problem constants
#define B_  16
#define T_  12
#define N_  1000
#define F_  64
#define KC  3
#define O_  64
#define NP  1024            // padded N (both i and j dims)
#define KP  (KC * NP)       // 3072 combined contraction length per b
#define CC  (T_ * O_)       // 768 output columns per b
#define NTK (KP / 32)       // 96 K-tiles of 32 for stage-3 GEMM

typedef __bf16 bf16x8 __attribute__((ext_vector_type(8)));
typedef float  f32x4  __attribute__((ext_vector_type(4)));

__device__ __forceinline__ unsigned short f2bf(float f) {
  __bf16 h = (__bf16)f;                      // RNE convert
  return __builtin_bit_cast(unsigned short, h);
}

// async global->LDS, 16B per lane. LDS dest = wave-uniform base + lane*16.
__device__ __forceinline__ void gl_lds16(const void* g, void* l) {
  __builtin_amdgcn_global_load_lds(
      (const __attribute__((address_space(1))) unsigned int*)g,
      (__attribute__((address_space(3))) unsigned int*)l,
      16, 0, 0);
}

// ---------------------------------------------------------------------------
// Stage 1: ASt[b][ip][k][jp] = bf16(cheb[k,j,i] * SAtt[b,j,i]), zero-padded.
// 64x64 (j x i) tile, transpose via LDS. float4 loads, uint4 stores.
// grid (i-tile, j-tile, b) = (16,16,16)
// ---------------------------------------------------------------------------
__global__ __launch_bounds__(256) void k_build_as(
    const float* __restrict__ SAtt, const float* __restrict__ cheb,
    unsigned short* __restrict__ ASt) {
  __shared__ unsigned short prod[KC][64][66];   // 66 -> 132B rows (4B aligned)
  const int tid = threadIdx.x;
  const int b = blockIdx.z, ib = blockIdx.x * 64, jb = blockIdx.y * 64;

  // load phase: float4 along i (contiguous dim), 16 j-rows per pass
  const int ii4 = (tid & 15) * 4, jr = tid >> 4;
#pragma unroll
  for (int p = 0; p < 4; ++p) {
    const int jj = p * 16 + jr;
    const int gj = jb + jj;
    const int gjc = gj < N_ ? gj : N_ - 1;
    const int gi = ib + ii4;                    // N_%4==0: f4 never straddles
    const bool iok = gi < N_;
    const bool ok = iok && (gj < N_);
    float4 s4 = make_float4(0.f, 0.f, 0.f, 0.f);
    if (iok) s4 = *(const float4*)&SAtt[((size_t)b * N_ + gjc) * N_ + gi];
#pragma unroll
    for (int k = 0; k < KC; ++k) {
      float4 c4 = make_float4(0.f, 0.f, 0.f, 0.f);
      if (iok) c4 = *(const float4*)&cheb[((size_t)k * N_ + gjc) * N_ + gi];
      ushort2 lo, hi;
      lo.x = ok ? f2bf(c4.x * s4.x) : (unsigned short)0;
      lo.y = ok ? f2bf(c4.y * s4.y) : (unsigned short)0;
      hi.x = ok ? f2bf(c4.z * s4.z) : (unsigned short)0;
      hi.y = ok ? f2bf(c4.w * s4.w) : (unsigned short)0;
      *(ushort2*)&prod[k][jj][ii4]     = lo;
      *(ushort2*)&prod[k][jj][ii4 + 2] = hi;
    }
  }
  __syncthreads();

  // write phase: uint4 (8 bf16, 16B) per lane along j; 32 i-rows per pass
  const int j8 = (tid & 7) * 8, i0 = tid >> 3;
#pragma unroll
  for (int p = 0; p < 2; ++p) {
    const int iw = p * 32 + i0;
#pragma unroll
    for (int k = 0; k < KC; ++k) {
      unsigned short v[8];
#pragma unroll
      for (int m = 0; m < 8; ++m) v[m] = prod[k][j8 + m][iw];
      *(uint4*)&ASt[((size_t)(b * NP + ib + iw) * KC + k) * NP + jb + j8] =
          *(uint4*)v;
    }
  }
}

// ---------------------------------------------------------------------------
// Stage 2: Yt[b][t][o][k][jp] = bf16(sum_f x[b,t,j,f] * Theta[k,f,o]).
// MFMA A = Theta^T (M=o=64), B = x (N=j=128), K=f=64. Epilogue via LDS tile
// so global stores are uint4 (16B) coalesced. grid (j-tile, b*T) = (8, 192).
// ---------------------------------------------------------------------------
__global__ __launch_bounds__(256) void k_build_y(
    const float* __restrict__ x, const float* __restrict__ Theta,
    unsigned short* __restrict__ Yt) {
  __shared__ unsigned short thl[KC][64][72];  // Theta^T [k][o][f]
  __shared__ unsigned short xl[128][72];      // x tile [j][f]
  __shared__ unsigned short ot[64][136];      // out tile [o][j], 16B-aligned rows
  const int tid = threadIdx.x;
  const int bt = blockIdx.y;                  // b*T + t
  const int jb = blockIdx.x * 128;

  // Theta -> thl (transposed): float4 loads along o, scalar LDS writes
#pragma unroll
  for (int it = 0; it < 12; ++it) {
    const int e = (tid + it * 256) * 4;       // element index, mult of 4
    const int k = e >> 12, f = (e >> 6) & 63, o0 = e & 63;
    const float4 v = *(const float4*)&Theta[e];
    thl[k][o0 + 0][f] = f2bf(v.x);
    thl[k][o0 + 1][f] = f2bf(v.y);
    thl[k][o0 + 2][f] = f2bf(v.z);
    thl[k][o0 + 3][f] = f2bf(v.w);
  }
  // x chunk (128 j-rows x 64 f) -> xl as bf16, float4 loads
  const float* xrow = x + ((size_t)bt * N_ + jb) * F_;
#pragma unroll
  for (int p = 0; p < 8; ++p) {
    const int i4 = tid + p * 256;            // float4 index, 0..2047
    const int fl = i4 * 4, j = fl >> 6, f = fl & 63;
    float4 v;
    if (jb + j < N_) v = ((const float4*)xrow)[i4];
    else             v = make_float4(0.f, 0.f, 0.f, 0.f);
    ushort4 u;
    u.x = f2bf(v.x); u.y = f2bf(v.y); u.z = f2bf(v.z); u.w = f2bf(v.w);
    *(ushort4*)&xl[j][f] = u;
  }
  __syncthreads();

  const int w = tid >> 6, l = tid & 63, quad = l >> 4, lr = l & 15;
  const int o16 = tid >> 4, j8v = (tid & 15) * 8;
#pragma unroll
  for (int k = 0; k < KC; ++k) {
    f32x4 acc[4][2];
#pragma unroll
    for (int mi = 0; mi < 4; ++mi)
#pragma unroll
      for (int ni = 0; ni < 2; ++ni)
        acc[mi][ni] = (f32x4){0.f, 0.f, 0.f, 0.f};
#pragma unroll
    for (int ks = 0; ks < 2; ++ks) {
      const int fo = ks * 32 + quad * 8;
      bf16x8 a[4], bb[2];
#pragma unroll
      for (int mi = 0; mi < 4; ++mi)
        a[mi] = *(const bf16x8*)&thl[k][mi * 16 + lr][fo];
#pragma unroll
      for (int ni = 0; ni < 2; ++ni)
        bb[ni] = *(const bf16x8*)&xl[w * 32 + ni * 16 + lr][fo];
#pragma unroll
      for (int mi = 0; mi < 4; ++mi)
#pragma unroll
        for (int ni = 0; ni < 2; ++ni)
          acc[mi][ni] = __builtin_amdgcn_mfma_f32_16x16x32_bf16(
              a[mi], bb[ni], acc[mi][ni], 0, 0, 0);
    }
    __syncthreads();                          // protect ot from prior readers
#pragma unroll
    for (int mi = 0; mi < 4; ++mi)
#pragma unroll
      for (int ni = 0; ni < 2; ++ni)
#pragma unroll
        for (int r = 0; r < 4; ++r)
          ot[mi * 16 + quad * 4 + r][w * 32 + ni * 16 + lr] =
              f2bf(acc[mi][ni][r]);
    __syncthreads();
    // coalesced stores: 16 lanes x 16B = 256B contiguous per o-row
#pragma unroll
    for (int oo = 0; oo < 4; ++oo) {
      const int o = oo * 16 + o16;
      const uint4 v = *(const uint4*)&ot[o][j8v];
      *(uint4*)&Yt[((size_t)(bt * O_ + o) * KC + k) * NP + jb + j8v] = v;
    }
  }
}

// ---------------------------------------------------------------------------
// Stage 3: per-b GEMM  C[i,c] = sum_{K'} ASt[b][i][K'] * Yt[b][c][K'],
// M=1024(i), N=768(c), K=3072. 8-phase-class schedule:
//   256x192 tile, 8 waves (2Mx4N, per-wave 128x48), BK=32.
//   4 LDS buffers (112 KB), 3-K-tile prefetch lead, counted vmcnt (never 0
//   in main loop), T2 chunk-XOR swizzle (pre-swizzled global src + linear
//   global_load_lds dest + XOR'd ds_read), T5 setprio around MFMA clusters.
// grid = 256 blocks (16 b x 4 ib x 4 cb) = exactly 1 block/CU, 512 threads.
// ---------------------------------------------------------------------------
__global__ __launch_bounds__(512, 2) void k_gemm(
    const unsigned short* __restrict__ ASt, const unsigned short* __restrict__ Yt,
    float* __restrict__ out) {
  __shared__ unsigned short Al[4][256][32];   // 64 KB, 64B rows, 4 K-tile bufs
  __shared__ unsigned short Bl[4][192][32];   // 48 KB

  const int tid = threadIdx.x;
  const int bid = blockIdx.x;
  // XCD swizzle: bid%8 -> XCD; all 16 tiles of a given b land on one XCD
  const int xcd = bid & 7, s = bid >> 3;      // s = 0..31
  const int b = xcd * 2 + (s >> 4);
  const int r = s & 15;
  const int ib = (r >> 2) * 256;              // 4 i-tiles of 256
  const int cb = (r & 3) * 192;               // 4 c-tiles of 192

  const unsigned short* Abase = ASt + ((size_t)b * NP + ib) * KP;
  const unsigned short* Bbase = Yt + ((size_t)b * CC + cb) * KP;

  const int w = tid >> 6, l = tid & 63;
  const int quad = l >> 4, lr = l & 15;
  const int wr = w >> 2, wc = w & 3;          // 2M x 4N wave grid

  // staging: per-lane pre-swizzled source chunk (elements). LDS dest linear.
  // LDS[row][cphys] holds global chunk cphys ^ ((row>>1)&3).
  const int xc8 = ((((l >> 3) & 3) ^ (l & 3)) * 8);
  const int rA0 = w * 16 + (l >> 2), rA1 = 128 + rA0;  // A rows, 2 sweeps
  const int rB0 = rA0, rB1 = 96 + rB0;                 // B rows (waves 0..5)
  unsigned short* const al0 = &Al[0][0][0];
  unsigned short* const bl0 = &Bl[0][0][0];

  // read side: physical chunk for logical k-chunk `quad` at row (...16k + lr)
  const int pq = (quad ^ ((lr >> 1) & 3)) * 8;
  const int arow = lr * 32 + pq;

  f32x4 acc[8][3];
#pragma unroll
  for (int mi = 0; mi < 8; ++mi)
#pragma unroll
    for (int ni = 0; ni < 3; ++ni) acc[mi][ni] = (f32x4){0.f, 0.f, 0.f, 0.f};

#define STAGE(kt_)                                                            \
  {                                                                           \
    const int bufi_ = (kt_) & 3;                                              \
    const size_t k0_ = (size_t)(kt_) * 32 + xc8;                              \
    gl_lds16(Abase + (size_t)rA0 * KP + k0_, al0 + bufi_ * 8192 + w * 512);   \
    gl_lds16(Abase + (size_t)rA1 * KP + k0_,                                  \
             al0 + bufi_ * 8192 + (8 + w) * 512);                             \
    if (w < 6) {                                                              \
      gl_lds16(Bbase + (size_t)rB0 * KP + k0_, bl0 + bufi_ * 6144 + w * 512); \
      gl_lds16(Bbase + (size_t)rB1 * KP + k0_,                                \
               bl0 + bufi_ * 6144 + (6 + w) * 512);                           \
    }                                                                         \
  }

  // counted waits: retire kt+1's loads, keep kt+2/kt+3 in flight (per-wave
  // FIFO: w<6 issues 4 loads per K-tile, w>=6 issues 2)
#define WAITBAR()                                                    \
  __builtin_amdgcn_sched_barrier(0);                                 \
  if (w < 6) asm volatile("s_waitcnt vmcnt(8)" ::: "memory");        \
  else       asm volatile("s_waitcnt vmcnt(4)" ::: "memory");        \
  __builtin_amdgcn_s_barrier();                                      \
  __builtin_amdgcn_sched_barrier(0);

  STAGE(0); STAGE(1); STAGE(2);
  WAITBAR();                                  // K-tile 0 landed

  for (int kt = 0; kt < NTK; ++kt) {
    if (kt + 3 < NTK) STAGE(kt + 3);          // into buffer freed by kt-1
    const unsigned short* Ab = al0 + (kt & 3) * 8192 + (wr * 128) * 32;
    const unsigned short* Bb = bl0 + (kt & 3) * 6144 + (wc * 48) * 32;
    bf16x8 afr[4], bfr[3];
#pragma unroll
    for (int ni = 0; ni < 3; ++ni)
      bfr[ni] = *(const bf16x8*)&Bb[ni * 512 + arow];
#pragma unroll
    for (int mi = 0; mi < 4; ++mi)
      afr[mi] = *(const bf16x8*)&Ab[mi * 512 + arow];
    __builtin_amdgcn_s_setprio(1);
#pragma unroll
    for (int mi = 0; mi < 4; ++mi)
#pragma unroll
      for (int ni = 0; ni < 3; ++ni)
        acc[mi][ni] = __builtin_amdgcn_mfma_f32_16x16x32_bf16(
            afr[mi], bfr[ni], acc[mi][ni], 0, 0, 0);
    __builtin_amdgcn_s_setprio(0);
#pragma unroll
    for (int mi = 0; mi < 4; ++mi)
      afr[mi] = *(const bf16x8*)&Ab[(4 + mi) * 512 + arow];
    __builtin_amdgcn_s_setprio(1);
#pragma unroll
    for (int mi = 0; mi < 4; ++mi)
#pragma unroll
      for (int ni = 0; ni < 3; ++ni)
        acc[4 + mi][ni] = __builtin_amdgcn_mfma_f32_16x16x32_bf16(
            afr[mi], bfr[ni], acc[4 + mi][ni], 0, 0, 0);
    __builtin_amdgcn_s_setprio(0);
    WAITBAR();                                // kt+1 landed for next iter
  }
#undef STAGE
#undef WAITBAR

  // epilogue: C/D layout col=lane&15 (->c), row=quad*4+reg (->i). ReLU fused.
#pragma unroll
  for (int mi = 0; mi < 8; ++mi) {
    const int i0 = ib + wr * 128 + mi * 16 + quad * 4;
#pragma unroll
    for (int ni = 0; ni < 3; ++ni) {
      const int c = cb + wc * 48 + ni * 16 + lr;
      const int t = c >> 6, o = c & 63;
#pragma unroll
      for (int rr = 0; rr < 4; ++rr) {
        const int i = i0 + rr;
        if (i < N_) {
          const float v = acc[mi][ni][rr];
          out[((size_t)(b * T_ + t) * N_ + i) * O_ + o] = v > 0.f ? v : 0.f;
        }
      }
    }
  }
}

// ---------------------------------------------------------------------------
extern "C" void kernel_launch(void* const* d_in, const int* in_sizes, int n_in,
                              void* d_out, int out_size, void* d_ws, size_t ws_size,
                              hipStream_t stream) {
  const float* x     = (const float*)d_in[0];
  const float* SAtt  = (const float*)d_in[1];
  const float* cheb  = (const float*)d_in[2];
  const float* Theta = (const float*)d_in[3];
  float* out = (float*)d_out;

  unsigned short* ASt = (unsigned short*)d_ws;                 // 100.7 MB
  unsigned short* Yt  = ASt + (size_t)B_ * NP * KC * NP;       //  75.5 MB

  k_build_as<<<dim3(16, 16, B_), 256, 0, stream>>>(SAtt, cheb, ASt);
  k_build_y<<<dim3(8, B_ * T_), 256, 0, stream>>>(x, Theta, Yt);
  k_gemm<<<256, 512, 0, stream>>>(ASt, Yt, out);
}

// Round 2
// 330.980 us; speedup vs baseline: 1.0066x; 1.0066x over previous
//
#include <hip/hip_runtime.h>

// Problem constants
#define B_  16
#define T_  12
#define N_  1000
#define F_  64
#define KC  3
#define O_  64
#define NP  1024            // padded N (both i and j dims)
#define KP  (KC * NP)       // 3072 combined contraction length per b
#define CC  (T_ * O_)       // 768 output columns per b
#define NT64 (KP / 64)      // 48 K-tiles of 64 for stage-3 GEMM

typedef __bf16 bf16x8 __attribute__((ext_vector_type(8)));
typedef float  f32x4  __attribute__((ext_vector_type(4)));

__device__ __forceinline__ unsigned short f2bf(float f) {
  __bf16 h = (__bf16)f;                      // RNE convert
  return __builtin_bit_cast(unsigned short, h);
}

// async global->LDS, 16B per lane. LDS dest = wave-uniform base + lane*16.
__device__ __forceinline__ void gl_lds16(const void* g, void* l) {
  __builtin_amdgcn_global_load_lds(
      (const __attribute__((address_space(1))) unsigned int*)g,
      (__attribute__((address_space(3))) unsigned int*)l,
      16, 0, 0);
}

// ---------------------------------------------------------------------------
// Stage 1: ASt[b][ip][k][jp] = bf16(cheb[k,j,i] * SAtt[b,j,i]), zero-padded.
// ---------------------------------------------------------------------------
__global__ __launch_bounds__(256) void k_build_as(
    const float* __restrict__ SAtt, const float* __restrict__ cheb,
    unsigned short* __restrict__ ASt) {
  __shared__ unsigned short prod[KC][64][66];   // 66 -> 132B rows (4B aligned)
  const int tid = threadIdx.x;
  const int b = blockIdx.z, ib = blockIdx.x * 64, jb = blockIdx.y * 64;

  const int ii4 = (tid & 15) * 4, jr = tid >> 4;
#pragma unroll
  for (int p = 0; p < 4; ++p) {
    const int jj = p * 16 + jr;
    const int gj = jb + jj;
    const int gjc = gj < N_ ? gj : N_ - 1;
    const int gi = ib + ii4;                    // N_%4==0: f4 never straddles
    const bool iok = gi < N_;
    const bool ok = iok && (gj < N_);
    float4 s4 = make_float4(0.f, 0.f, 0.f, 0.f);
    if (iok) s4 = *(const float4*)&SAtt[((size_t)b * N_ + gjc) * N_ + gi];
#pragma unroll
    for (int k = 0; k < KC; ++k) {
      float4 c4 = make_float4(0.f, 0.f, 0.f, 0.f);
      if (iok) c4 = *(const float4*)&cheb[((size_t)k * N_ + gjc) * N_ + gi];
      ushort2 lo, hi;
      lo.x = ok ? f2bf(c4.x * s4.x) : (unsigned short)0;
      lo.y = ok ? f2bf(c4.y * s4.y) : (unsigned short)0;
      hi.x = ok ? f2bf(c4.z * s4.z) : (unsigned short)0;
      hi.y = ok ? f2bf(c4.w * s4.w) : (unsigned short)0;
      *(ushort2*)&prod[k][jj][ii4]     = lo;
      *(ushort2*)&prod[k][jj][ii4 + 2] = hi;
    }
  }
  __syncthreads();

  const int j8 = (tid & 7) * 8, i0 = tid >> 3;
#pragma unroll
  for (int p = 0; p < 2; ++p) {
    const int iw = p * 32 + i0;
#pragma unroll
    for (int k = 0; k < KC; ++k) {
      unsigned short v[8];
#pragma unroll
      for (int m = 0; m < 8; ++m) v[m] = prod[k][j8 + m][iw];
      *(uint4*)&ASt[((size_t)(b * NP + ib + iw) * KC + k) * NP + jb + j8] =
          *(uint4*)v;
    }
  }
}

// ---------------------------------------------------------------------------
// Stage 2: Yt[b][t][o][k][jp] = bf16(sum_f x[b,t,j,f] * Theta[k,f,o]).
// ---------------------------------------------------------------------------
__global__ __launch_bounds__(256) void k_build_y(
    const float* __restrict__ x, const float* __restrict__ Theta,
    unsigned short* __restrict__ Yt) {
  __shared__ unsigned short thl[KC][64][72];  // Theta^T [k][o][f]
  __shared__ unsigned short xl[128][72];      // x tile [j][f]
  __shared__ unsigned short ot[64][136];      // out tile [o][j]
  const int tid = threadIdx.x;
  const int bt = blockIdx.y;                  // b*T + t
  const int jb = blockIdx.x * 128;

#pragma unroll
  for (int it = 0; it < 12; ++it) {
    const int e = (tid + it * 256) * 4;       // element index, mult of 4
    const int k = e >> 12, f = (e >> 6) & 63, o0 = e & 63;
    const float4 v = *(const float4*)&Theta[e];
    thl[k][o0 + 0][f] = f2bf(v.x);
    thl[k][o0 + 1][f] = f2bf(v.y);
    thl[k][o0 + 2][f] = f2bf(v.z);
    thl[k][o0 + 3][f] = f2bf(v.w);
  }
  const float* xrow = x + ((size_t)bt * N_ + jb) * F_;
#pragma unroll
  for (int p = 0; p < 8; ++p) {
    const int i4 = tid + p * 256;            // float4 index, 0..2047
    const int fl = i4 * 4, j = fl >> 6, f = fl & 63;
    float4 v;
    if (jb + j < N_) v = ((const float4*)xrow)[i4];
    else             v = make_float4(0.f, 0.f, 0.f, 0.f);
    ushort4 u;
    u.x = f2bf(v.x); u.y = f2bf(v.y); u.z = f2bf(v.z); u.w = f2bf(v.w);
    *(ushort4*)&xl[j][f] = u;
  }
  __syncthreads();

  const int w = tid >> 6, l = tid & 63, quad = l >> 4, lr = l & 15;
  const int o16 = tid >> 4, j8v = (tid & 15) * 8;
#pragma unroll
  for (int k = 0; k < KC; ++k) {
    f32x4 acc[4][2];
#pragma unroll
    for (int mi = 0; mi < 4; ++mi)
#pragma unroll
      for (int ni = 0; ni < 2; ++ni)
        acc[mi][ni] = (f32x4){0.f, 0.f, 0.f, 0.f};
#pragma unroll
    for (int ks = 0; ks < 2; ++ks) {
      const int fo = ks * 32 + quad * 8;
      bf16x8 a[4], bb[2];
#pragma unroll
      for (int mi = 0; mi < 4; ++mi)
        a[mi] = *(const bf16x8*)&thl[k][mi * 16 + lr][fo];
#pragma unroll
      for (int ni = 0; ni < 2; ++ni)
        bb[ni] = *(const bf16x8*)&xl[w * 32 + ni * 16 + lr][fo];
#pragma unroll
      for (int mi = 0; mi < 4; ++mi)
#pragma unroll
        for (int ni = 0; ni < 2; ++ni)
          acc[mi][ni] = __builtin_amdgcn_mfma_f32_16x16x32_bf16(
              a[mi], bb[ni], acc[mi][ni], 0, 0, 0);
    }
    __syncthreads();
#pragma unroll
    for (int mi = 0; mi < 4; ++mi)
#pragma unroll
      for (int ni = 0; ni < 2; ++ni)
#pragma unroll
        for (int r = 0; r < 4; ++r)
          ot[mi * 16 + quad * 4 + r][w * 32 + ni * 16 + lr] =
              f2bf(acc[mi][ni][r]);
    __syncthreads();
#pragma unroll
    for (int oo = 0; oo < 4; ++oo) {
      const int o = oo * 16 + o16;
      const uint4 v = *(const uint4*)&ot[o][j8v];
      *(uint4*)&Yt[((size_t)(bt * O_ + o) * KC + k) * NP + jb + j8v] = v;
    }
  }
}

// ---------------------------------------------------------------------------
// Stage 3: per-b GEMM  C[i,c] = sum_{K'} ASt[b][i][K'] * Yt[b][c][K'],
// M=1024(i), N=768(c), K=3072. Faithful m201-style 8-phase schedule:
//   BM=256, BN=192, BK=64; 8 waves (2Mx4N, per-wave 128x48).
//   4 phases per K-tile: {7|4 ds_read_b128, 2|1 gl_lds sweeps, barrier,
//   lgkmcnt(0), setprio(1), 12 MFMA, setprio(0), [vmcnt(2)], barrier}.
//   Counted vmcnt(2) at phase-1/4 close (per-wave FIFO: 7 sweeps/K-tile,
//   ordered B0,B64,B128,A0,A128,A64,A192 so ph1 consumes first 5, ph2 last 2).
//   XOR swizzle: phys chunk = logical ^ (row&7); pre-swizzled global source,
//   linear gl_lds dest, XOR'd ds_read -> conflict-free b128 reads.
// grid = 256 blocks (16 b x 4 ib x 4 cb) = 1 block/CU, 512 threads, 112KB LDS.
// ---------------------------------------------------------------------------
__global__ __launch_bounds__(512, 2) void k_gemm(
    const unsigned short* __restrict__ ASt, const unsigned short* __restrict__ Yt,
    float* __restrict__ out) {
  __shared__ unsigned short Al[2][256][64];   // 64 KB (2 bufs, 128B rows)
  __shared__ unsigned short Bl[2][192][64];   // 48 KB

  const int tid = threadIdx.x;
  const int bid = blockIdx.x;
  // XCD swizzle: bid%8 -> XCD; 2 b's per XCD; same-ib cb-tiles adjacent
  const int xcd = bid & 7, s = bid >> 3;      // s = 0..31
  const int b = xcd * 2 + (s >> 4);
  const int r = s & 15;
  const int ib = (r >> 2) * 256;              // 4 i-tiles of 256
  const int cb = (r & 3) * 192;               // 4 c-tiles of 192

  const unsigned short* Abase = ASt + ((size_t)b * NP + ib) * KP;
  const unsigned short* Bbase = Yt + ((size_t)b * CC + cb) * KP;

  const int w = tid >> 6, l = tid & 63;
  const int quad = l >> 4, lr = l & 15, lr7 = lr & 7;
  const int wr = w >> 2, wc = w & 3;          // 2M x 4N wave grid
  const int w8 = w * 8;

  // staging invariants: sweep = 512 lanes x 16B = 64 rows x 128B
  const int rsw = tid >> 3;                              // row within sweep
  const int xcs = ((tid & 7) ^ (rsw & 7)) * 8;           // pre-swizzled chunk
  const unsigned short* gA = Abase + (size_t)rsw * KP + xcs;
  const unsigned short* gB = Bbase + (size_t)rsw * KP + xcs;

  // read side: phys chunk offsets (ushort) for ks=0 / ks=1
  const int pq0 = ((quad) ^ lr7) * 8;
  const int pq1 = ((4 + quad) ^ lr7) * 8;

  f32x4 acc[8][3];
#pragma unroll
  for (int mi = 0; mi < 8; ++mi)
#pragma unroll
    for (int ni = 0; ni < 3; ++ni) acc[mi][ni] = (f32x4){0.f, 0.f, 0.f, 0.f};
  bf16x8 afr[4], bfr[3];

#define SWA(bf_, ra_, k0_) \
  gl_lds16(gA + (size_t)(ra_) * KP + (k0_), &Al[bf_][(ra_) + w8][0])
#define SWB(bf_, rb_, k0_) \
  gl_lds16(gB + (size_t)(rb_) * KP + (k0_), &Bl[bf_][(rb_) + w8][0])

#define PH_OPEN()                                          \
  __builtin_amdgcn_sched_barrier(0);                       \
  __builtin_amdgcn_s_barrier();                            \
  asm volatile("s_waitcnt lgkmcnt(0)" ::: "memory");       \
  __builtin_amdgcn_sched_barrier(0)

#define PH_CLOSE()                                         \
  __builtin_amdgcn_sched_barrier(0);                       \
  __builtin_amdgcn_s_barrier();                            \
  __builtin_amdgcn_sched_barrier(0)

#define PH_CLOSE_VM2()                                     \
  __builtin_amdgcn_sched_barrier(0);                       \
  asm volatile("s_waitcnt vmcnt(2)" ::: "memory");         \
  __builtin_amdgcn_s_barrier();                            \
  __builtin_amdgcn_sched_barrier(0)

#define MFMA12(OFF_)                                                       \
  __builtin_amdgcn_s_setprio(1);                                           \
  _Pragma("unroll") for (int mi = 0; mi < 4; ++mi)                         \
      _Pragma("unroll") for (int ni = 0; ni < 3; ++ni)                     \
          acc[(OFF_) + mi][ni] = __builtin_amdgcn_mfma_f32_16x16x32_bf16(  \
              afr[mi], bfr[ni], acc[(OFF_) + mi][ni], 0, 0, 0);            \
  __builtin_amdgcn_s_setprio(0)

  // one K-tile = 4 phases. C_: LDS buf (compile-time), KT_: tile index,
  // ST_: stage tile KT_+1, LAST_: drain (final tile) at ph1 close.
#define TILE(C_, KT_, ST_, LAST_)                                             \
  {                                                                           \
    const int k1 = ((KT_) + 1) * 64;                                          \
    /* phase 1: B ks0 (3) + A mi0-3 ks0 (4); stage B0,B64 */                  \
    _Pragma("unroll") for (int ni = 0; ni < 3; ++ni)                          \
        bfr[ni] = *(const bf16x8*)&Bl[C_][wc * 48 + ni * 16 + lr][pq0];       \
    _Pragma("unroll") for (int mi = 0; mi < 4; ++mi)                          \
        afr[mi] = *(const bf16x8*)&Al[C_][wr * 128 + mi * 16 + lr][pq0];      \
    if (ST_) { SWB(C_ ^ 1, 0, k1); SWB(C_ ^ 1, 64, k1); }                     \
    PH_OPEN();                                                                \
    MFMA12(0);                                                                \
    __builtin_amdgcn_sched_barrier(0);                                        \
    if (LAST_) { asm volatile("s_waitcnt vmcnt(0)" ::: "memory"); }           \
    else       { asm volatile("s_waitcnt vmcnt(2)" ::: "memory"); }           \
    __builtin_amdgcn_s_barrier();                                             \
    __builtin_amdgcn_sched_barrier(0);                                        \
    /* phase 2: A mi4-7 ks0 (4, B reused); stage B128,A0 */                   \
    _Pragma("unroll") for (int mi = 0; mi < 4; ++mi)                          \
        afr[mi] = *(const bf16x8*)&Al[C_][wr * 128 + (4 + mi) * 16 + lr][pq0];\
    if (ST_) { SWB(C_ ^ 1, 128, k1); SWA(C_ ^ 1, 0, k1); }                    \
    PH_OPEN();                                                                \
    MFMA12(4);                                                                \
    PH_CLOSE();                                                               \
    /* phase 3: B ks1 (3) + A mi0-3 ks1 (4); stage A128,A64 */                \
    _Pragma("unroll") for (int ni = 0; ni < 3; ++ni)                          \
        bfr[ni] = *(const bf16x8*)&Bl[C_][wc * 48 + ni * 16 + lr][pq1];       \
    _Pragma("unroll") for (int mi = 0; mi < 4; ++mi)                          \
        afr[mi] = *(const bf16x8*)&Al[C_][wr * 128 + mi * 16 + lr][pq1];      \
    if (ST_) { SWA(C_ ^ 1, 128, k1); SWA(C_ ^ 1, 64, k1); }                   \
    PH_OPEN();                                                                \
    MFMA12(0);                                                                \
    PH_CLOSE();                                                               \
    /* phase 4: A mi4-7 ks1 (4); stage A192 */                                \
    _Pragma("unroll") for (int mi = 0; mi < 4; ++mi)                          \
        afr[mi] = *(const bf16x8*)&Al[C_][wr * 128 + (4 + mi) * 16 + lr][pq1];\
    if (ST_) { SWA(C_ ^ 1, 192, k1); }                                        \
    PH_OPEN();                                                                \
    MFMA12(4);                                                                \
    PH_CLOSE_VM2();                                                           \
  }

  // prologue: stage tile 0 (7 sweeps, consumption order), land first 5
  SWB(0, 0, 0); SWB(0, 64, 0); SWB(0, 128, 0);
  SWA(0, 0, 0); SWA(0, 128, 0); SWA(0, 64, 0); SWA(0, 192, 0);
  __builtin_amdgcn_sched_barrier(0);
  asm volatile("s_waitcnt vmcnt(2)" ::: "memory");
  __builtin_amdgcn_s_barrier();
  __builtin_amdgcn_sched_barrier(0);

#pragma unroll 1
  for (int kt2 = 0; kt2 < NT64 / 2; ++kt2) {
    TILE(0, kt2 * 2, true, false);
    TILE(1, kt2 * 2 + 1, (kt2 < NT64 / 2 - 1), (kt2 == NT64 / 2 - 1));
  }
#undef TILE
#undef MFMA12
#undef PH_OPEN
#undef PH_CLOSE
#undef PH_CLOSE_VM2
#undef SWA
#undef SWB

  // epilogue: C/D layout col=lane&15 (->c), row=quad*4+reg (->i). ReLU fused.
#pragma unroll
  for (int mi = 0; mi < 8; ++mi) {
    const int i0 = ib + wr * 128 + mi * 16 + quad * 4;
#pragma unroll
    for (int ni = 0; ni < 3; ++ni) {
      const int c = cb + wc * 48 + ni * 16 + lr;
      const int t = c >> 6, o = c & 63;
#pragma unroll
      for (int rr = 0; rr < 4; ++rr) {
        const int i = i0 + rr;
        if (i < N_) {
          const float v = acc[mi][ni][rr];
          out[((size_t)(b * T_ + t) * N_ + i) * O_ + o] = v > 0.f ? v : 0.f;
        }
      }
    }
  }
}

// ---------------------------------------------------------------------------
extern "C" void kernel_launch(void* const* d_in, const int* in_sizes, int n_in,
                              void* d_out, int out_size, void* d_ws, size_t ws_size,
                              hipStream_t stream) {
  const float* x     = (const float*)d_in[0];
  const float* SAtt  = (const float*)d_in[1];
  const float* cheb  = (const float*)d_in[2];
  const float* Theta = (const float*)d_in[3];
  float* out = (float*)d_out;

  unsigned short* ASt = (unsigned short*)d_ws;                 // 100.7 MB
  unsigned short* Yt  = ASt + (size_t)B_ * NP * KC * NP;       //  75.5 MB

  k_build_as<<<dim3(16, 16, B_), 256, 0, stream>>>(SAtt, cheb, ASt);
  k_build_y<<<dim3(8, B_ * T_), 256, 0, stream>>>(x, Theta, Yt);
  k_gemm<<<256, 512, 0, stream>>>(ASt, Yt, out);
}

// Round 3
// 308.777 us; speedup vs baseline: 1.0790x; 1.0719x over previous
//
#include <hip/hip_runtime.h>

// Problem constants
#define B_  16
#define T_  12
#define N_  1000
#define F_  64
#define KC  3
#define O_  64
#define NP  1024            // padded N (both i and j dims)
#define KP  (KC * NP)       // 3072 combined contraction length per b
#define CC  (T_ * O_)       // 768 output columns per b

typedef __bf16 bf16x8 __attribute__((ext_vector_type(8)));
typedef float  f32x4  __attribute__((ext_vector_type(4)));

__device__ __forceinline__ unsigned short f2bf(float f) {
  __bf16 h = (__bf16)f;                      // RNE convert
  return __builtin_bit_cast(unsigned short, h);
}

// async global->LDS, 16B per lane. LDS dest = wave-uniform base + lane*16.
__device__ __forceinline__ void gl_lds16(const void* g, void* l) {
  __builtin_amdgcn_global_load_lds(
      (const __attribute__((address_space(1))) unsigned int*)g,
      (__attribute__((address_space(3))) unsigned int*)l,
      16, 0, 0);
}

// ---------------------------------------------------------------------------
// Stage 1: ASt[b][ip][k][jp] = bf16(cheb[k,j,i] * SAtt[b,j,i]), zero-padded.
// b-batched 8x: cheb tile preloaded into registers (12 float4, held across
// the b-loop), SAtt streamed per b. 64x64 (j x i) tile, transpose via LDS.
// grid (i-tile, j-tile, b-group) = (16,16,2), 256 threads.
// ---------------------------------------------------------------------------
__global__ __launch_bounds__(256) void k_build_as(
    const float* __restrict__ SAtt, const float* __restrict__ cheb,
    unsigned short* __restrict__ ASt) {
  __shared__ unsigned short prod[KC][64][66];   // 66 -> 132B rows (4B aligned)
  const int tid = threadIdx.x;
  const int ib = blockIdx.x * 64, jb = blockIdx.y * 64;

  // load-phase geometry: float4 along i (contiguous dim), 16 j-rows per pass
  const int ii4 = (tid & 15) * 4, jr = tid >> 4;
  const int gi = ib + ii4;                      // N_%4==0: f4 never straddles
  const bool iok = gi < N_;

  // preload cheb tile into registers: 4 passes x 3 k = 48 VGPR
  float4 ch[4][KC];
  int gjc[4];
  bool okm[4];
#pragma unroll
  for (int p = 0; p < 4; ++p) {
    const int gj = jb + p * 16 + jr;
    gjc[p] = gj < N_ ? gj : N_ - 1;
    okm[p] = iok && (gj < N_);
#pragma unroll
    for (int k = 0; k < KC; ++k) {
      ch[p][k] = make_float4(0.f, 0.f, 0.f, 0.f);
      if (iok)
        ch[p][k] = *(const float4*)&cheb[((size_t)k * N_ + gjc[p]) * N_ + gi];
    }
  }

  // write-phase geometry: uint4 (8 bf16) per lane along j; 32 i-rows per pass
  const int j8 = (tid & 7) * 8, i0 = tid >> 3;

  for (int bb = 0; bb < 8; ++bb) {
    const int b = blockIdx.z * 8 + bb;
    const float* sb = SAtt + (size_t)b * N_ * N_;
    if (bb) __syncthreads();      // protect prod from prior transpose readers
#pragma unroll
    for (int p = 0; p < 4; ++p) {
      const int jj = p * 16 + jr;
      float4 s4 = make_float4(0.f, 0.f, 0.f, 0.f);
      if (iok) s4 = *(const float4*)&sb[(size_t)gjc[p] * N_ + gi];
#pragma unroll
      for (int k = 0; k < KC; ++k) {
        ushort2 lo, hi;
        lo.x = okm[p] ? f2bf(ch[p][k].x * s4.x) : (unsigned short)0;
        lo.y = okm[p] ? f2bf(ch[p][k].y * s4.y) : (unsigned short)0;
        hi.x = okm[p] ? f2bf(ch[p][k].z * s4.z) : (unsigned short)0;
        hi.y = okm[p] ? f2bf(ch[p][k].w * s4.w) : (unsigned short)0;
        *(ushort2*)&prod[k][jj][ii4]     = lo;
        *(ushort2*)&prod[k][jj][ii4 + 2] = hi;
      }
    }
    __syncthreads();
#pragma unroll
    for (int pp = 0; pp < 2; ++pp) {
      const int iw = pp * 32 + i0;
#pragma unroll
      for (int k = 0; k < KC; ++k) {
        unsigned short v[8];
#pragma unroll
        for (int m = 0; m < 8; ++m) v[m] = prod[k][j8 + m][iw];
        *(uint4*)&ASt[((size_t)(b * NP + ib + iw) * KC + k) * NP + jb + j8] =
            *(uint4*)v;
      }
    }
  }
}

// ---------------------------------------------------------------------------
// Stage 2: Yt[b][t][o][k][jp] = bf16(sum_f x[b,t,j,f] * Theta[k,f,o]).
// t-batched 3x: Theta^T staged to LDS once per block, then 3 t's processed.
// MFMA A = Theta^T (M=o=64), B = x (N=j=128), K=f=64. Epilogue via LDS tile
// so global stores are uint4 (16B) coalesced.
// grid (j-tile, b, t-group) = (8, 16, 4), 256 threads.
// ---------------------------------------------------------------------------
__global__ __launch_bounds__(256) void k_build_y(
    const float* __restrict__ x, const float* __restrict__ Theta,
    unsigned short* __restrict__ Yt) {
  __shared__ unsigned short thl[KC][64][72];  // Theta^T [k][o][f]
  __shared__ unsigned short xl[128][72];      // x tile [j][f]
  __shared__ unsigned short ot[64][136];      // out tile [o][j]
  const int tid = threadIdx.x;
  const int jb = blockIdx.x * 128;

  // Theta -> thl (transposed): float4 loads along o, scalar LDS writes
#pragma unroll
  for (int it = 0; it < 12; ++it) {
    const int e = (tid + it * 256) * 4;       // element index, mult of 4
    const int k = e >> 12, f = (e >> 6) & 63, o0 = e & 63;
    const float4 v = *(const float4*)&Theta[e];
    thl[k][o0 + 0][f] = f2bf(v.x);
    thl[k][o0 + 1][f] = f2bf(v.y);
    thl[k][o0 + 2][f] = f2bf(v.z);
    thl[k][o0 + 3][f] = f2bf(v.w);
  }

  const int w = tid >> 6, l = tid & 63, quad = l >> 4, lr = l & 15;
  const int o16 = tid >> 4, j8v = (tid & 15) * 8;

  for (int tt = 0; tt < 3; ++tt) {
    const int bt = blockIdx.y * T_ + blockIdx.z * 3 + tt;
    // x chunk (128 j-rows x 64 f) -> xl as bf16, float4 loads.
    // Safe without a leading barrier: previous iteration's xl readers all
    // passed its k=2 first barrier; ot readers don't touch xl.
    const float* xrow = x + ((size_t)bt * N_ + jb) * F_;
#pragma unroll
    for (int p = 0; p < 8; ++p) {
      const int i4 = tid + p * 256;            // float4 index, 0..2047
      const int fl = i4 * 4, j = fl >> 6, f = fl & 63;
      float4 v;
      if (jb + j < N_) v = ((const float4*)xrow)[i4];
      else             v = make_float4(0.f, 0.f, 0.f, 0.f);
      ushort4 u;
      u.x = f2bf(v.x); u.y = f2bf(v.y); u.z = f2bf(v.z); u.w = f2bf(v.w);
      *(ushort4*)&xl[j][f] = u;
    }
    __syncthreads();

#pragma unroll
    for (int k = 0; k < KC; ++k) {
      f32x4 acc[4][2];
#pragma unroll
      for (int mi = 0; mi < 4; ++mi)
#pragma unroll
        for (int ni = 0; ni < 2; ++ni)
          acc[mi][ni] = (f32x4){0.f, 0.f, 0.f, 0.f};
#pragma unroll
      for (int ks = 0; ks < 2; ++ks) {
        const int fo = ks * 32 + quad * 8;
        bf16x8 a[4], bb[2];
#pragma unroll
        for (int mi = 0; mi < 4; ++mi)
          a[mi] = *(const bf16x8*)&thl[k][mi * 16 + lr][fo];
#pragma unroll
        for (int ni = 0; ni < 2; ++ni)
          bb[ni] = *(const bf16x8*)&xl[w * 32 + ni * 16 + lr][fo];
#pragma unroll
        for (int mi = 0; mi < 4; ++mi)
#pragma unroll
          for (int ni = 0; ni < 2; ++ni)
            acc[mi][ni] = __builtin_amdgcn_mfma_f32_16x16x32_bf16(
                a[mi], bb[ni], acc[mi][ni], 0, 0, 0);
      }
      __syncthreads();                          // protect ot from prior readers
#pragma unroll
      for (int mi = 0; mi < 4; ++mi)
#pragma unroll
        for (int ni = 0; ni < 2; ++ni)
#pragma unroll
          for (int r = 0; r < 4; ++r)
            ot[mi * 16 + quad * 4 + r][w * 32 + ni * 16 + lr] =
                f2bf(acc[mi][ni][r]);
      __syncthreads();
      // coalesced stores: 16 lanes x 16B = 256B contiguous per o-row
#pragma unroll
      for (int oo = 0; oo < 4; ++oo) {
        const int o = oo * 16 + o16;
        const uint4 v = *(const uint4*)&ot[o][j8v];
        *(uint4*)&Yt[((size_t)(bt * O_ + o) * KC + k) * NP + jb + j8v] = v;
      }
    }
  }
}

// ---------------------------------------------------------------------------
// Stage 3: per-b GEMM  C[i,c] = sum_{K'} ASt[b][i][K'] * Yt[b][c][K'],
// M=1024(i), N=768(c), K=3072. 128x128 tile, 4 waves x (64x64), 16x16x32 bf16
// MFMA, BK=64, global_load_lds width-16. XOR chunk swizzle kills the 16-way
// LDS bank conflict of the 128B row stride. XCD-aware block swizzle (2 b/XCD).
// (round-0 verified version, 120 us)
// ---------------------------------------------------------------------------
__global__ __launch_bounds__(256, 2) void k_gemm(
    const unsigned short* __restrict__ ASt, const unsigned short* __restrict__ Yt,
    float* __restrict__ out) {
  __shared__ unsigned short Al[128 * 64];   // [row][K-chunk swizzled], 16 KB
  __shared__ unsigned short Bl[128 * 64];
  const int tid = threadIdx.x;
  // block swizzle: bid%8 -> XCD (HW round-robin heuristic); 2 b's per XCD
  const int bid = blockIdx.x;
  const int xcd = bid & 7, s = bid >> 3;          // s = 0..95
  const int b = xcd * 2 + (s / 48);
  const int r48 = s % 48;
  const int ib = (r48 / 6) * 128, cb = (r48 % 6) * 128;

  const unsigned short* Abase = ASt + ((size_t)b * NP + ib) * KP;
  const unsigned short* Bbase = Yt + ((size_t)b * CC + cb) * KP;
  const int w = tid >> 6, l = tid & 63, quad = l >> 4, lr = l & 15;
  const int wr = w & 1, wc = w >> 1;
  const int lrow = l >> 3, lchunk = l & 7;
  const int src_chunk = lchunk ^ lrow;            // XOR swizzle (staging side)
  const int p0 = quad ^ (lr & 7);                 // phys chunk, ks=0 (read side)

  f32x4 acc[4][4];
#pragma unroll
  for (int mi = 0; mi < 4; ++mi)
#pragma unroll
    for (int ci = 0; ci < 4; ++ci)
      acc[mi][ci] = (f32x4){0.f, 0.f, 0.f, 0.f};

  for (int kt = 0; kt < KP / 64; ++kt) {
    __syncthreads();                        // protect LDS from prior readers
    const int k0 = kt * 64;
#pragma unroll
    for (int s4 = 0; s4 < 4; ++s4) {
      const int row = w * 32 + s4 * 8;      // wave-uniform LDS base row
      gl_lds16(Abase + (size_t)(row + lrow) * KP + k0 + src_chunk * 8,
               &Al[row * 64]);
      gl_lds16(Bbase + (size_t)(row + lrow) * KP + k0 + src_chunk * 8,
               &Bl[row * 64]);
    }
    __syncthreads();                        // drains vmcnt(0) -> LDS valid
#pragma unroll
    for (int ks = 0; ks < 2; ++ks) {
      const int pc = (p0 ^ (ks * 4)) * 8;   // swizzled chunk -> ushort offset
      bf16x8 a[4], bb[4];
#pragma unroll
      for (int mi = 0; mi < 4; ++mi)
        a[mi] = *(const bf16x8*)&Al[(wr * 64 + mi * 16 + lr) * 64 + pc];
#pragma unroll
      for (int ci = 0; ci < 4; ++ci)
        bb[ci] = *(const bf16x8*)&Bl[(wc * 64 + ci * 16 + lr) * 64 + pc];
#pragma unroll
      for (int mi = 0; mi < 4; ++mi)
#pragma unroll
        for (int ci = 0; ci < 4; ++ci)
          acc[mi][ci] = __builtin_amdgcn_mfma_f32_16x16x32_bf16(
              a[mi], bb[ci], acc[mi][ci], 0, 0, 0);
    }
  }

  // epilogue: C/D layout col=lane&15 (->c), row=quad*4+reg (->i). ReLU fused.
#pragma unroll
  for (int mi = 0; mi < 4; ++mi) {
    const int i = ib + wr * 64 + mi * 16 + quad * 4;
#pragma unroll
    for (int ci = 0; ci < 4; ++ci) {
      const int c = cb + wc * 64 + ci * 16 + lr;
      const int t = c >> 6, o = c & 63;      // 16-aligned tile: single t
#pragma unroll
      for (int r = 0; r < 4; ++r) {
        if (i + r < N_) {
          const float v = acc[mi][ci][r];
          out[((size_t)(b * T_ + t) * N_ + (i + r)) * O_ + o] = v > 0.f ? v : 0.f;
        }
      }
    }
  }
}

// ---------------------------------------------------------------------------
extern "C" void kernel_launch(void* const* d_in, const int* in_sizes, int n_in,
                              void* d_out, int out_size, void* d_ws, size_t ws_size,
                              hipStream_t stream) {
  const float* x     = (const float*)d_in[0];
  const float* SAtt  = (const float*)d_in[1];
  const float* cheb  = (const float*)d_in[2];
  const float* Theta = (const float*)d_in[3];
  float* out = (float*)d_out;

  unsigned short* ASt = (unsigned short*)d_ws;                 // 100.7 MB
  unsigned short* Yt  = ASt + (size_t)B_ * NP * KC * NP;       //  75.5 MB

  k_build_as<<<dim3(16, 16, 2), 256, 0, stream>>>(SAtt, cheb, ASt);
  k_build_y<<<dim3(8, B_, 4), 256, 0, stream>>>(x, Theta, Yt);
  k_gemm<<<768, 256, 0, stream>>>(ASt, Yt, out);
}